// Round 13
// baseline (91.660 us; speedup 1.0000x reference)
//
#include <hip/hip_runtime.h>
#include <hip/hip_bf16.h>
#include <math.h>

#define NPAIR 4096       // N = B*S
#define D 128
#define TWO_N 8192
// Rb rows pre-scaled by ALPHA = sqrt(2*log2(e)): MFMA acc == 2*log2(e)*sim,
// so exp(2*sim) == exp2(acc) -> a single raw v_exp_f32 in the epilogue.
#define ALPHA 1.6986436f

typedef float f32x4 __attribute__((ext_vector_type(4)));
typedef int i32x8 __attribute__((ext_vector_type(8)));

__device__ __forceinline__ void async_ld16(void* lds, const void* g) {
    // async global->LDS DMA, 16B/lane; LDS dest = wave-uniform base + lane*16
    __builtin_amdgcn_global_load_lds(
        (__attribute__((address_space(1))) const unsigned int*)g,
        (__attribute__((address_space(3))) unsigned int*)lds, 16, 0, 0);
}

__device__ __forceinline__ i32x8 mk8(uint4 lo, uint4 hi) {
    return (i32x8){(int)lo.x, (int)lo.y, (int)lo.z, (int)lo.w,
                   (int)hi.x, (int)hi.y, (int)hi.z, (int)hi.w};
}

// 1024 blocks x 256 threads; wave w handles pair-row k = blockIdx*4 + w.
// Emits ALPHA-scaled fp8 e4m3 rows, plain row-major. pos[] exact fp32.
// Zero-inits rowsum[8192] (8/block), cnt[128] (block 0), out[0].
__global__ __launch_bounds__(256) void norm_kernel(const float* __restrict__ zi,
                                                   const float* __restrict__ zj,
                                                   unsigned char* __restrict__ Rb,
                                                   float* __restrict__ pos,
                                                   float* __restrict__ rowsum,
                                                   int* __restrict__ cnt,
                                                   float* __restrict__ out) {
    if (threadIdx.x < 8) rowsum[blockIdx.x * 8 + threadIdx.x] = 0.f;
    if (blockIdx.x == 0) {
        if (threadIdx.x >= 128 && threadIdx.x < 256) {
            // cnt[0..127] zero (tid 128..255)
            cnt[threadIdx.x - 128] = 0;
        }
        if (threadIdx.x == 8) out[0] = 0.f;
    }
    int k = blockIdx.x * 4 + (threadIdx.x >> 6);
    int t = threadIdx.x & 63;                 // 2 elems each
    const float2 a = *(const float2*)(zi + k * D + 2 * t);
    const float2 b = *(const float2*)(zj + k * D + 2 * t);
    float si = a.x * a.x + a.y * a.y;
    float sj = b.x * b.x + b.y * b.y;
    float dt = a.x * b.x + a.y * b.y;
    #pragma unroll
    for (int m = 1; m < 64; m <<= 1) {
        si += __shfl_xor(si, m, 64);
        sj += __shfl_xor(sj, m, 64);
        dt += __shfl_xor(dt, m, 64);
    }
    float ii = 1.0f / fmaxf(sqrtf(si), 1e-12f);
    float ij = 1.0f / fmaxf(sqrtf(sj), 1e-12f);
    if (t == 0) pos[k] = dt * ii * ij;        // exact (unscaled) positive sim
    ii *= ALPHA; ij *= ALPHA;
    int r0 = __builtin_amdgcn_cvt_pk_fp8_f32(a.x * ii, a.y * ii, 0, false);
    *(unsigned short*)(Rb + (size_t)k * 128 + 2 * t) = (unsigned short)r0;
    int r1 = __builtin_amdgcn_cvt_pk_fp8_f32(b.x * ij, b.y * ij, 0, false);
    *(unsigned short*)(Rb + (size_t)(k + NPAIR) * 128 + 2 * t) = (unsigned short)r1;
}

// R12 structure (MX-scaled fp8 x128 MFMA, zero barriers in the K-loop,
// wave-private 2KB triple-buffered panels, depth-2 prefetch, vmcnt(2)
// mid-loop, raw v_exp_f32) + FUSED FINALIZE:
//  - row partials flush via atomicAdd into rowsum[8192] (block-end only);
//  - per-stripe counters: the 8th (bi,jc) block to finish stripe bi computes
//    that stripe's 64 loss terms in wave 0 and atomicAdds one value to out.
// No separate finalize dispatch, no 1MB slab round-trip.
__global__ __launch_bounds__(256, 4) void simexp_kernel(const unsigned char* __restrict__ Rb,
                                                        float* __restrict__ rowsum,
                                                        int* __restrict__ cnt,
                                                        const float* __restrict__ pos,
                                                        float* __restrict__ out) {
    __shared__ uint4 Bs[4][3][128];      // [wave][buf][16 cols x 8 pieces] 2KB/buf
    __shared__ int oldv;
    const int bi = blockIdx.x >> 3;      // 0..127 (64-row stripe)
    const int jc = blockIdx.x & 7;       // 0..7  (1024-col slab)
    const int tid = threadIdx.x;
    const int wave = tid >> 6, lane = tid & 63;
    const int rp = lane & 15, q = lane >> 4;

    // A fragments: row = bi*64 + rt*16 + rp; lane's k [q*32, q*32+32).
    i32x8 afr[4];                        // [rt]
    {
        const unsigned char* Ab = Rb + (size_t)(bi * 64 + rp) * 128 + q * 32;
        #pragma unroll
        for (int rt = 0; rt < 4; ++rt) {
            uint4 h0 = *(const uint4*)(Ab + rt * 16 * 128);
            uint4 h1 = *(const uint4*)(Ab + rt * 16 * 128 + 16);
            afr[rt] = mk8(h0, h1);
        }
    }

    // Wave-private B panel: cols jc*1024 + jt*64 + wave*16 + [0,16), 128B/col,
    // 2 DMAs/jt (8 cols each). DMA d, lane l: col cr = d*8 + (l>>3), stored
    // piece p' = l&7, global piece p = p' ^ (cr&7)  [slot = cr*8 + (p^(cr&7))].
    const unsigned char* gslab = Rb + (size_t)(jc * 1024 + wave * 16) * 128;
    char* lpanel = (char*)&Bs[wave][0][0];
    const int laneoff = (lane >> 3) * 128 + (((lane & 7) ^ ((lane >> 3) & 7)) << 4);

    float rs[16];
    #pragma unroll
    for (int i = 0; i < 16; ++i) rs[i] = 0.f;

    // prefetch jt=0 (buf0) and jt=1 (buf1): 4 DMAs outstanding
    #pragma unroll
    for (int j = 0; j < 2; ++j)
        #pragma unroll
        for (int d = 0; d < 2; ++d)
            async_ld16(lpanel + j * 2048 + d * 1024,
                       gslab + j * 8192 + d * 1024 + laneoff);

    const int diagbase = bi * 64 - jc * 1024;   // diag col offset in slab
    const int slot0 = rp * 8;
    const int sw = rp & 7;

    #pragma unroll
    for (int jt = 0; jt < 16; ++jt) {
        // Wait only for the OLDEST panel (this jt's 2 DMAs); next stays in flight.
        if (jt < 14) __builtin_amdgcn_s_waitcnt(0x0F72);   // vmcnt(2)
        else         __builtin_amdgcn_s_waitcnt(0x0F70);   // vmcnt(0)

        const int cur = jt % 3;
        const uint4* P = &Bs[wave][cur][0];
        // lane needs col rp pieces 2q (k low half) and 2q+1 (k high half)
        uint4 u0 = P[slot0 + ((q * 2 + 0) ^ sw)];
        uint4 u1 = P[slot0 + ((q * 2 + 1) ^ sw)];
        i32x8 bfr = mk8(u0, u1);

        if (jt < 14) {                   // prefetch jt+2 into buf (jt+2)%3
            const int nb = (jt + 2) % 3;
            #pragma unroll
            for (int d = 0; d < 2; ++d)
                async_ld16(lpanel + nb * 2048 + d * 1024,
                           gslab + (jt + 2) * 8192 + d * 1024 + laneoff);
        }

        f32x4 acc[4] = {};
        #pragma unroll
        for (int rt = 0; rt < 4; ++rt)
            acc[rt] = __builtin_amdgcn_mfma_scale_f32_16x16x128_f8f6f4(
                afr[rt], bfr, acc[rt],
                0, 0,                     // cbsz=fp8(e4m3), blgp=fp8(e4m3)
                0, 0x7F7F7F7F,            // A scale opsel, scale = 1.0
                0, 0x7F7F7F7F);           // B scale opsel, scale = 1.0

        // D layout: col(tile-local) = wave*16 + rp, row = rt*16 + q*4 + r
        if (jt * 64 == diagbase) {       // the one jt tile holding the diagonal
            #pragma unroll
            for (int rt = 0; rt < 4; ++rt)
                #pragma unroll
                for (int r = 0; r < 4; ++r) {
                    int ro = rt * 16 + q * 4 + r;
                    int co = wave * 16 + rp;
                    float e = __builtin_amdgcn_exp2f(acc[rt][r]);
                    rs[rt * 4 + r] += (ro == co) ? 0.f : e;
                }
        } else {
            #pragma unroll
            for (int rt = 0; rt < 4; ++rt)
                #pragma unroll
                for (int r = 0; r < 4; ++r)
                    rs[rt * 4 + r] += __builtin_amdgcn_exp2f(acc[rt][r]);
        }
    }

    // Reduce each reg across the 16 rp lanes; rp==0 lanes atomically add
    // their 16 rows into rowsum (block-end only: ~256 lane-atomics/block).
    #pragma unroll
    for (int i = 0; i < 16; ++i) {
        float v = rs[i];
        v += __shfl_xor(v, 1, 64);
        v += __shfl_xor(v, 2, 64);
        v += __shfl_xor(v, 4, 64);
        v += __shfl_xor(v, 8, 64);
        rs[i] = v;
    }
    if (rp == 0) {
        const int rowb = bi * 64 + q * 4;
        #pragma unroll
        for (int rt = 0; rt < 4; ++rt)
            #pragma unroll
            for (int r = 0; r < 4; ++r)
                atomicAdd(&rowsum[rowb + rt * 16 + r], rs[rt * 4 + r]);
    }

    // Stripe-completion: the 8th finisher of stripe bi folds the stripe's 64
    // loss terms into out. threadfence orders our atomics before the inc;
    // atomic-read (add 0) gives a coherent cross-XCD view of rowsum.
    __syncthreads();
    if (tid == 0) {
        __threadfence();
        oldv = atomicAdd(&cnt[bi], 1);
    }
    __syncthreads();
    if (oldv == 7 && tid < 64) {
        int rgl = bi * 64 + tid;
        float rsum = atomicAdd(&rowsum[rgl], 0.0f);     // coherent read
        float ps = pos[rgl & (NPAIR - 1)];
        float p2 = ps + ps;
        float term = __logf(rsum + __expf(p2)) - p2;
        #pragma unroll
        for (int m = 1; m < 64; m <<= 1) term += __shfl_xor(term, m, 64);
        if (tid == 0) atomicAdd(out, term * (1.0f / (float)TWO_N));
    }
}

extern "C" void kernel_launch(void* const* d_in, const int* in_sizes, int n_in,
                              void* d_out, int out_size, void* d_ws, size_t ws_size,
                              hipStream_t stream) {
    const float* zi = (const float*)d_in[0];
    const float* zj = (const float*)d_in[1];
    char* ws = (char*)d_ws;
    unsigned char* Rb = (unsigned char*)ws;                         // 1 MB fp8 rows
    float* rowsum = (float*)(ws + 1024 * 1024);                     // 32 KB
    int* cnt = (int*)(ws + 1024 * 1024 + 32 * 1024);                // 512 B
    float* pos = (float*)(ws + 1024 * 1024 + 64 * 1024);            // 16 KB

    norm_kernel<<<NPAIR / 4, 256, 0, stream>>>(zi, zj, Rb, pos, rowsum, cnt, (float*)d_out);
    simexp_kernel<<<128 * 8, 256, 0, stream>>>(Rb, rowsum, cnt, pos, (float*)d_out);
}

// Round 14
// 77.298 us; speedup vs baseline: 1.1858x; 1.1858x over previous
//
#include <hip/hip_runtime.h>
#include <hip/hip_bf16.h>
#include <math.h>

#define NPAIR 4096       // N = B*S
#define D 128
#define TWO_N 8192
#define NSLAB 32         // 8 jc-slabs x 4 waves, race-free partial rows
// Rb rows pre-scaled by ALPHA = sqrt(2*log2(e)): MFMA acc == 2*log2(e)*sim,
// so exp(2*sim) == exp2(acc) -> a single raw v_exp_f32 in the epilogue.
#define ALPHA 1.6986436f

typedef float f32x4 __attribute__((ext_vector_type(4)));
typedef int i32x8 __attribute__((ext_vector_type(8)));

__device__ __forceinline__ void async_ld16(void* lds, const void* g) {
    // async global->LDS DMA, 16B/lane; LDS dest = wave-uniform base + lane*16
    __builtin_amdgcn_global_load_lds(
        (__attribute__((address_space(1))) const unsigned int*)g,
        (__attribute__((address_space(3))) unsigned int*)lds, 16, 0, 0);
}

__device__ __forceinline__ i32x8 mk8(uint4 lo, uint4 hi) {
    return (i32x8){(int)lo.x, (int)lo.y, (int)lo.z, (int)lo.w,
                   (int)hi.x, (int)hi.y, (int)hi.z, (int)hi.w};
}

// 1024 blocks x 256 threads; wave w handles pair-row k = blockIdx*4 + w.
// Emits ALPHA-scaled fp8 e4m3 rows, PLAIN ROW-MAJOR (byte b = element b):
// the x128 scaled MFMA wants each lane k-contiguous [q*32, q*32+32).
// pos[] stays exact fp32. Zero-inits out[0].
__global__ __launch_bounds__(256) void norm_kernel(const float* __restrict__ zi,
                                                   const float* __restrict__ zj,
                                                   unsigned char* __restrict__ Rb,
                                                   float* __restrict__ pos,
                                                   float* __restrict__ out) {
    if (blockIdx.x == 0 && threadIdx.x == 0) out[0] = 0.f;
    int k = blockIdx.x * 4 + (threadIdx.x >> 6);
    int t = threadIdx.x & 63;                 // 2 elems each
    const float2 a = *(const float2*)(zi + k * D + 2 * t);
    const float2 b = *(const float2*)(zj + k * D + 2 * t);
    float si = a.x * a.x + a.y * a.y;
    float sj = b.x * b.x + b.y * b.y;
    float dt = a.x * b.x + a.y * b.y;
    #pragma unroll
    for (int m = 1; m < 64; m <<= 1) {
        si += __shfl_xor(si, m, 64);
        sj += __shfl_xor(sj, m, 64);
        dt += __shfl_xor(dt, m, 64);
    }
    float ii = 1.0f / fmaxf(sqrtf(si), 1e-12f);
    float ij = 1.0f / fmaxf(sqrtf(sj), 1e-12f);
    if (t == 0) pos[k] = dt * ii * ij;        // exact (unscaled) positive sim
    ii *= ALPHA; ij *= ALPHA;
    int r0 = __builtin_amdgcn_cvt_pk_fp8_f32(a.x * ii, a.y * ii, 0, false);
    *(unsigned short*)(Rb + (size_t)k * 128 + 2 * t) = (unsigned short)r0;
    int r1 = __builtin_amdgcn_cvt_pk_fp8_f32(b.x * ij, b.y * ij, 0, false);
    *(unsigned short*)(Rb + (size_t)(k + NPAIR) * 128 + 2 * t) = (unsigned short)r1;
}

// R12 structure + DEPTH-3 prefetch through a QUAD buffer: panels jt..jt+2
// always in flight (6 DMAs), loop-top wait vmcnt(4) drains only the oldest
// panel -> lookahead ~3 compute phases > L2 DMA latency. 1024 blocks:
// bi = b>>3 (64-row stripe), jc = b&7 (1024-col slab, 16 jt tiles of 64
// cols). ZERO BARRIERS; wave-private 2KB panels; MX-scaled fp8 x128 MFMA
// (scale=1.0); raw v_exp_f32 epilogue; XOR-swizzled conflict-free LDS.
__global__ __launch_bounds__(256, 4) void simexp_kernel(const unsigned char* __restrict__ Rb,
                                                        float* __restrict__ rspart) {
    __shared__ uint4 Bs[4][4][128];      // [wave][buf][16 cols x 8 pieces] 2KB/buf
    const int bi = blockIdx.x >> 3;      // 0..127 (64-row stripe)
    const int jc = blockIdx.x & 7;       // 0..7  (1024-col slab)
    const int tid = threadIdx.x;
    const int wave = tid >> 6, lane = tid & 63;
    const int rp = lane & 15, q = lane >> 4;

    // A fragments: row = bi*64 + rt*16 + rp; lane's k [q*32, q*32+32).
    i32x8 afr[4];                        // [rt]
    {
        const unsigned char* Ab = Rb + (size_t)(bi * 64 + rp) * 128 + q * 32;
        #pragma unroll
        for (int rt = 0; rt < 4; ++rt) {
            uint4 h0 = *(const uint4*)(Ab + rt * 16 * 128);
            uint4 h1 = *(const uint4*)(Ab + rt * 16 * 128 + 16);
            afr[rt] = mk8(h0, h1);
        }
    }

    // Wave-private B panel: cols jc*1024 + jt*64 + wave*16 + [0,16), 128B/col,
    // 2 DMAs/jt (8 cols each). DMA d, lane l: col cr = d*8 + (l>>3), stored
    // piece p' = l&7, global piece p = p' ^ (cr&7)  [slot = cr*8 + (p^(cr&7))].
    const unsigned char* gslab = Rb + (size_t)(jc * 1024 + wave * 16) * 128;
    char* lpanel = (char*)&Bs[wave][0][0];
    const int laneoff = (lane >> 3) * 128 + (((lane & 7) ^ ((lane >> 3) & 7)) << 4);

    float rs[16];
    #pragma unroll
    for (int i = 0; i < 16; ++i) rs[i] = 0.f;

    // prefetch jt=0,1,2 (bufs 0,1,2): 6 DMAs outstanding
    #pragma unroll
    for (int j = 0; j < 3; ++j)
        #pragma unroll
        for (int d = 0; d < 2; ++d)
            async_ld16(lpanel + j * 2048 + d * 1024,
                       gslab + j * 8192 + d * 1024 + laneoff);

    const int diagbase = bi * 64 - jc * 1024;   // diag col offset in slab
    const int slot0 = rp * 8;
    const int sw = rp & 7;

    #pragma unroll
    for (int jt = 0; jt < 16; ++jt) {
        // Drain only the OLDEST panel; the two newer ones stay in flight.
        if (jt < 14)       __builtin_amdgcn_s_waitcnt(0x0F74);   // vmcnt(4)
        else if (jt == 14) __builtin_amdgcn_s_waitcnt(0x0F72);   // vmcnt(2)
        else               __builtin_amdgcn_s_waitcnt(0x0F70);   // vmcnt(0)

        const int cur = jt & 3;
        const uint4* P = &Bs[wave][cur][0];
        // lane needs col rp pieces 2q (k low half) and 2q+1 (k high half)
        uint4 u0 = P[slot0 + ((q * 2 + 0) ^ sw)];
        uint4 u1 = P[slot0 + ((q * 2 + 1) ^ sw)];
        i32x8 bfr = mk8(u0, u1);

        if (jt < 13) {                   // prefetch jt+3 into buf (jt+3)&3
            const int nb = (jt + 3) & 3;
            #pragma unroll
            for (int d = 0; d < 2; ++d)
                async_ld16(lpanel + nb * 2048 + d * 1024,
                           gslab + (jt + 3) * 8192 + d * 1024 + laneoff);
        }

        f32x4 acc[4] = {};
        #pragma unroll
        for (int rt = 0; rt < 4; ++rt)
            acc[rt] = __builtin_amdgcn_mfma_scale_f32_16x16x128_f8f6f4(
                afr[rt], bfr, acc[rt],
                0, 0,                     // cbsz=fp8(e4m3), blgp=fp8(e4m3)
                0, 0x7F7F7F7F,            // A scale opsel, scale = 1.0
                0, 0x7F7F7F7F);           // B scale opsel, scale = 1.0

        // D layout: col(tile-local) = wave*16 + rp, row = rt*16 + q*4 + r
        if (jt * 64 == diagbase) {       // the one jt tile holding the diagonal
            #pragma unroll
            for (int rt = 0; rt < 4; ++rt)
                #pragma unroll
                for (int r = 0; r < 4; ++r) {
                    int ro = rt * 16 + q * 4 + r;
                    int co = wave * 16 + rp;
                    float e = __builtin_amdgcn_exp2f(acc[rt][r]);
                    rs[rt * 4 + r] += (ro == co) ? 0.f : e;
                }
        } else {
            #pragma unroll
            for (int rt = 0; rt < 4; ++rt)
                #pragma unroll
                for (int r = 0; r < 4; ++r)
                    rs[rt * 4 + r] += __builtin_amdgcn_exp2f(acc[rt][r]);
        }
    }

    // Reduce each reg across the 16 rp lanes; rp==0 stores its 16 rows.
    #pragma unroll
    for (int i = 0; i < 16; ++i) {
        float v = rs[i];
        v += __shfl_xor(v, 1, 64);
        v += __shfl_xor(v, 2, 64);
        v += __shfl_xor(v, 4, 64);
        v += __shfl_xor(v, 8, 64);
        rs[i] = v;
    }
    if (rp == 0) {
        const int slab = jc * 4 + wave;
        const int rowb = bi * 64 + q * 4;
        #pragma unroll
        for (int rt = 0; rt < 4; ++rt)
            #pragma unroll
            for (int r = 0; r < 4; ++r)
                rspart[slab * TWO_N + rowb + rt * 16 + r] = rs[rt * 4 + r];
    }
}

// 16 blocks x 256 threads; each thread does 2 rows; one atomicAdd per block.
__global__ __launch_bounds__(256) void finalize_kernel(const float* __restrict__ rspart,
                                                       const float* __restrict__ pos,
                                                       float* __restrict__ out) {
    __shared__ float red[4];
    int tid = threadIdx.x;
    float local = 0.f;
    #pragma unroll
    for (int i = 0; i < 2; ++i) {
        int k = blockIdx.x * 512 + i * 256 + tid;
        float rsum = 0.f;
        #pragma unroll
        for (int p = 0; p < NSLAB; ++p) rsum += rspart[p * TWO_N + k];
        float ps = pos[k & (NPAIR - 1)];
        float p2 = ps + ps;
        local += logf(rsum + __expf(p2)) - p2;
    }
    #pragma unroll
    for (int m = 1; m < 64; m <<= 1) local += __shfl_xor(local, m, 64);
    if ((tid & 63) == 0) red[tid >> 6] = local;
    __syncthreads();
    if (tid == 0) {
        float s = red[0] + red[1] + red[2] + red[3];
        atomicAdd(out, s * (1.0f / (float)TWO_N));
    }
}

extern "C" void kernel_launch(void* const* d_in, const int* in_sizes, int n_in,
                              void* d_out, int out_size, void* d_ws, size_t ws_size,
                              hipStream_t stream) {
    const float* zi = (const float*)d_in[0];
    const float* zj = (const float*)d_in[1];
    char* ws = (char*)d_ws;
    unsigned char* Rb = (unsigned char*)ws;                         // 1 MB fp8 rows
    float* rspart = (float*)(ws + 1 * 1024 * 1024);                 // 32*8192*4 = 1 MB
    float* pos = (float*)(ws + 2 * 1024 * 1024);                    // 16 KB

    norm_kernel<<<NPAIR / 4, 256, 0, stream>>>(zi, zj, Rb, pos, (float*)d_out);
    simexp_kernel<<<128 * 8, 256, 0, stream>>>(Rb, rspart);
    finalize_kernel<<<16, 256, 0, stream>>>(rspart, pos, (float*)d_out);
}